// Round 4
// baseline (342.692 us; speedup 1.0000x reference)
//
#include <hip/hip_runtime.h>
#include <cstdint>
#include <cstddef>

// Problem: B=4, S=4096, HID=1024, H=16, DH=64
//   qkv = query @ W^T + b    (M=16384, N=3072, K=1024)
//   per-position (b,s): scores = q(16x64) @ k^T /8 + mask(16x16); softmax; o = p @ v(16x64)
// Pipeline: cast fp32->bf16 (query, W) -> MFMA GEMM (bf16, fp32 acc, +bias, store bf16)
//           -> per-position attention (bf16 K/V staged via global_load_lds) -> out fp32.
//
// GEMM: 256x256 tile, BK=64, 8 waves (2M x 4N), classic lead-1-window double buffer with
// ONE __syncthreads per window and NO intra-window barriers/waits:
//   window t: __syncthreads()            // implicit vmcnt(0)+lgkmcnt(0): tile t ready
//                                        // (its DMAs issued at top of t-1: ~full-window
//                                        // lead >> HBM latency, so zero expected stall),
//                                        // and buf[nxt]'s window-(t-1) reads published.
//             STAGE tile t+1 -> buf[nxt] // 8 global_load_lds x16B per thread; disjoint
//                                        // from buf[cur], so NO intra-window hazard.
//             READ B8 + A-chunks (two named register sets, ping-pong) interleaved with
//             4 MFMA clusters (16 each, setprio-wrapped).  Compiler inserts counted
//             lgkmcnt gates; waves drift freely within the window so each wave's
//             ds_reads hide under other waves' MFMAs (per-phase lockstep barriers were
//             serializing read-bursts against MFMA-bursts CU-wide: R1/R2 ~1400cyc/phase).
// Race-freedom is by buffer disjointness + the single barrier's full drain - independent
// of compiler scheduling and of any wait arithmetic.
// LDS tiles keep the proven 16B-chunk XOR swizzle (slot = chunk ^ (row&7)): 0 conflicts.
// ws layout: Qb bf16 [16M el] @0 ; Wb bf16 [3M el] @33554432 ; QKVb bf16 [48M el] @39845888

typedef __attribute__((ext_vector_type(8))) short bf16x8;
typedef __attribute__((ext_vector_type(4))) float f32x4;

__device__ inline unsigned short f2bf(float f) {
  unsigned int i = __float_as_uint(f);
  i += 0x7fff + ((i >> 16) & 1);   // RNE
  return (unsigned short)(i >> 16);
}

__device__ inline void async16(const void* g, void* l) {
  __builtin_amdgcn_global_load_lds(
      (const __attribute__((address_space(1))) void*)g,
      (__attribute__((address_space(3))) void*)l, 16, 0, 0);
}

// unpack 8 packed bf16 -> 8 fp32
__device__ inline void unpack8(bf16x8 v, float* f) {
  union { bf16x8 s; unsigned int u[4]; } x; x.s = v;
  #pragma unroll
  for (int i = 0; i < 4; ++i) {
    f[2 * i]     = __uint_as_float(x.u[i] << 16);
    f[2 * i + 1] = __uint_as_float(x.u[i] & 0xffff0000u);
  }
}

// ---------------- cast fp32 -> bf16, 4 elems/thread ----------------
__global__ __launch_bounds__(256) void cast_kernel(const float* __restrict__ in,
                                                   unsigned short* __restrict__ out,
                                                   int n) {
  int i = (blockIdx.x * 256 + threadIdx.x) * 4;
  if (i >= n) return;
  float4 v = *(const float4*)(in + i);
  union { unsigned short u[4]; unsigned long long ll; } o;
  o.u[0] = f2bf(v.x); o.u[1] = f2bf(v.y); o.u[2] = f2bf(v.z); o.u[3] = f2bf(v.w);
  *(unsigned long long*)(out + i) = o.ll;
}

// ---------------- GEMM: C[M=16384][N=3072] = A[M][1024] * B[N][1024]^T + bias ----------------
#define GK 1024
#define GN 3072
__global__ __launch_bounds__(512, 2) void gemm_qkv(const unsigned short* __restrict__ A,
                                                   const unsigned short* __restrict__ Bm,
                                                   const float* __restrict__ bias,
                                                   unsigned short* __restrict__ C) {
  // double-buffered 256x64 tiles of A and B: 2 * 2 * 32 KiB = 128 KiB LDS
  __shared__ unsigned short As[2][256][64];
  __shared__ unsigned short Bs[2][256][64];

  // XCD-bijective swizzle (768 blocks % 8 == 0), n-fast within each XCD chunk:
  // each XCD touches 8 A-panels (4 MB) and streams the 6 MB B (L3-resident).
  const int bid = blockIdx.x;
  const int swz = (bid & 7) * 96 + (bid >> 3);
  const int m0 = (swz / 12) * 256;
  const int n0 = (swz % 12) * 256;

  const int tid  = threadIdx.x;
  const int lane = tid & 63;
  const int wave = tid >> 6;
  const int wm = wave & 1;        // 2 waves in M
  const int wn = wave >> 1;       // 4 waves in N
  const int fr = lane & 15;
  const int fq = lane >> 4;

  // staging geometry: slot = rho*512 + tid; row = slot>>3; chunk = (slot&7)^(row&7).
  // 8 lanes covering one row read a permuted-but-complete 128B segment: coalesced.
  const int r0 = tid >> 3;
  const int c0 = (tid & 7) ^ (r0 & 7);
  const unsigned short* gA = A  + (size_t)(m0 + r0) * GK + c0 * 8;
  const unsigned short* gB = Bm + (size_t)(n0 + r0) * GK + c0 * 8;
  const int ls0 = wave * 512;     // wave-uniform LDS element base (round 0); round 1: +4096

  // stage one 128-row half (2 DMA rounds) of tile tt into buffer (tt&1)
#define STAGE_A(tt, hh) do {                                                   \
    unsigned short* lb_ = &As[(tt) & 1][(hh) * 128][0];                        \
    const unsigned short* g_ = gA + (size_t)(hh) * 128 * GK + (tt) * 64;       \
    async16(g_, lb_ + ls0);                                                    \
    async16(g_ + (size_t)64 * GK, lb_ + 4096 + ls0);                           \
  } while (0)
#define STAGE_B(tt, hh) do {                                                   \
    unsigned short* lb_ = &Bs[(tt) & 1][(hh) * 128][0];                        \
    const unsigned short* g_ = gB + (size_t)(hh) * 128 * GK + (tt) * 64;       \
    async16(g_, lb_ + ls0);                                                    \
    async16(g_ + (size_t)64 * GK, lb_ + 4096 + ls0);                           \
  } while (0)

  // 4 A-fragment reads (chunk ph: rows [64*ph, 64*ph+64) via interleaved map) into AF
#define READ_A4(AF, bp, ph) do {                                               \
    _Pragma("unroll")                                                          \
    for (int ii = 0; ii < 2; ++ii) {                                           \
      const int rA = ((ph) * 2 + ii) * 32 + wm * 16 + fr;                      \
      _Pragma("unroll")                                                        \
      for (int ks = 0; ks < 2; ++ks)                                           \
        AF[ii][ks] = *(const bf16x8*)&As[bp][rA][((ks * 4 + fq) ^ (rA & 7)) * 8]; \
    } } while (0)

  // 8 B-fragment reads (whole window) from buffer bp
#define READ_B8(bp) do {                                                       \
    _Pragma("unroll")                                                          \
    for (int j = 0; j < 4; ++j) {                                              \
      const int rB = wn * 64 + j * 16 + fr;                                    \
      _Pragma("unroll")                                                        \
      for (int ks = 0; ks < 2; ++ks)                                           \
        bfr[j][ks] = *(const bf16x8*)&Bs[bp][rB][((ks * 4 + fq) ^ (rB & 7)) * 8]; \
    } } while (0)

#define MFMA16(ph, AF) do {                                                    \
    __builtin_amdgcn_s_setprio(1);                                             \
    _Pragma("unroll")                                                          \
    for (int ks = 0; ks < 2; ++ks)                                             \
      _Pragma("unroll")                                                        \
      for (int ii = 0; ii < 2; ++ii)                                           \
        _Pragma("unroll")                                                      \
        for (int j = 0; j < 4; ++j)                                            \
          acc[(ph) * 2 + ii][j] = __builtin_amdgcn_mfma_f32_16x16x32_bf16(     \
              AF[ii][ks], bfr[j][ks], acc[(ph) * 2 + ii][j], 0, 0, 0);         \
    __builtin_amdgcn_s_setprio(0);                                             \
  } while (0)

  f32x4 acc[8][4] = {};
  bf16x8 af0[2][2], af1[2][2];   // ping-pong A-chunk register sets (static indexing)
  bf16x8 bfr[4][2];              // B fragments, window-resident

  // prologue: stage tile 0 only; the loop's first __syncthreads drains it.
  STAGE_A(0, 0); STAGE_A(0, 1); STAGE_B(0, 0); STAGE_B(0, 1);

  for (int t = 0; t < 16; ++t) {
    const int cur = t & 1;
    __syncthreads();   // vmcnt(0)+lgkmcnt(0) drain: tile t ready, buf[nxt] reads done
    if (t + 1 < 16) {  // stage tile t+1 into the other buffer (disjoint from cur)
      STAGE_A(t + 1, 0); STAGE_A(t + 1, 1); STAGE_B(t + 1, 0); STAGE_B(t + 1, 1);
    }
    READ_B8(cur);
    READ_A4(af0, cur, 0);
    READ_A4(af1, cur, 1);
    MFMA16(0, af0);
    READ_A4(af0, cur, 2);
    MFMA16(1, af1);
    READ_A4(af1, cur, 3);
    MFMA16(2, af0);
    MFMA16(3, af1);
  }
#undef STAGE_A
#undef STAGE_B
#undef READ_A4
#undef READ_B8
#undef MFMA16

  // epilogue: bias + bf16 store (no barrier needed; all data in regs).
  // i-outer / j / rr-inner: the two 32B halves of each 64B C-line are written
  // 4 stores apart (measured clean 98 MB WRITE_SIZE in this order; j-outer
  // measured 187 MB from partial-line RMW).
  #pragma unroll
  for (int i = 0; i < 8; ++i) {
    #pragma unroll
    for (int j = 0; j < 4; ++j) {
      const int col = n0 + wn * 64 + j * 16 + fr;
      const float bc = bias[col];
      const int rowb = m0 + i * 32 + wm * 16 + fq * 4;
      #pragma unroll
      for (int rr = 0; rr < 4; ++rr)
        C[(size_t)(rowb + rr) * GN + col] = f2bf(acc[i][j][rr] + bc);
    }
  }
}

// ---------------- per-position attention ----------------
// one wave per position; lane = h*4 + dg (h = lane>>2, dg = lane&3).
// K/V staged to LDS as bf16 via global_load_lds (wave-private region, no syncthreads).
__global__ __launch_bounds__(256) void attn_kernel(const unsigned short* __restrict__ QKV,
                                                   const float* __restrict__ mask,
                                                   float* __restrict__ out) {
  __shared__ unsigned short shKV[4][2048];   // per wave: K [0..1023], V [1024..2047]
  const int wave = threadIdx.x >> 6;
  const int lane = threadIdx.x & 63;
  const int pos = blockIdx.x * 4 + wave;

  const unsigned short* row = QKV + (size_t)pos * 3072;

  // ---- stage K+V (2048 bf16 = 4 KB) via 4 DMA chunks
  #pragma unroll
  for (int t = 0; t < 4; ++t)
    async16(&row[1024 + t * 512 + (size_t)lane * 8], &shKV[wave][t * 512]);

  // ---- q slice from global: row[lane*16 .. +16)  (coalesced 32B/lane)
  bf16x8 q0 = *(const bf16x8*)&row[lane * 16];
  bf16x8 q1 = *(const bf16x8*)&row[lane * 16 + 8];

  const int h = lane >> 2;
  const int dg = lane & 3;

  const float* mrow = mask + (size_t)pos * 256 + h * 16;
  float4 m4[4];
  #pragma unroll
  for (int t = 0; t < 4; ++t) m4[t] = *(const float4*)&mrow[t * 4];

  float q[16];
  unpack8(q0, q);
  unpack8(q1, q + 8);

  asm volatile("s_waitcnt vmcnt(0)" ::: "memory");

  float s[16];
  #pragma unroll
  for (int g = 0; g < 16; ++g) {
    const unsigned short* kp = &shKV[wave][g * 64 + dg * 16];
    float kf[16];
    unpack8(*(const bf16x8*)kp, kf);
    unpack8(*(const bf16x8*)(kp + 8), kf + 8);
    float acc = 0.f;
    #pragma unroll
    for (int d = 0; d < 16; ++d) acc += q[d] * kf[d];
    s[g] = acc;
  }
  #pragma unroll
  for (int g = 0; g < 16; ++g) {
    s[g] += __shfl_xor(s[g], 1);
    s[g] += __shfl_xor(s[g], 2);
  }

  const float* mp = (const float*)m4;
  float mx = -1e30f;
  #pragma unroll
  for (int g = 0; g < 16; ++g) {
    s[g] = s[g] * 0.125f + mp[g];
    mx = fmaxf(mx, s[g]);
  }
  float sum = 0.f;
  #pragma unroll
  for (int g = 0; g < 16; ++g) { s[g] = __expf(s[g] - mx); sum += s[g]; }
  float inv = 1.f / sum;

  float o[16];
  #pragma unroll
  for (int dd = 0; dd < 16; ++dd) o[dd] = 0.f;
  #pragma unroll
  for (int g = 0; g < 16; ++g) {
    const unsigned short* vp = &shKV[wave][1024 + g * 64 + dg * 16];
    float vf[16];
    unpack8(*(const bf16x8*)vp, vf);
    unpack8(*(const bf16x8*)(vp + 8), vf + 8);
    float p = s[g];
    #pragma unroll
    for (int dd = 0; dd < 16; ++dd) o[dd] += p * vf[dd];
  }

  float* op = out + (size_t)pos * 1024 + lane * 16;
  #pragma unroll
  for (int t = 0; t < 4; ++t) {
    float4 w;
    w.x = o[t * 4 + 0] * inv; w.y = o[t * 4 + 1] * inv;
    w.z = o[t * 4 + 2] * inv; w.w = o[t * 4 + 3] * inv;
    *(float4*)(op + t * 4) = w;
  }
}

extern "C" void kernel_launch(void* const* d_in, const int* in_sizes, int n_in,
                              void* d_out, int out_size, void* d_ws, size_t ws_size,
                              hipStream_t stream) {
  const float* query = (const float*)d_in[0];
  // d_in[1] (key) and d_in[2] (value) are unused by the reference.
  const float* mask  = (const float*)d_in[3];
  const float* Wqkv  = (const float*)d_in[4];
  const float* bqkv  = (const float*)d_in[5];
  float* out = (float*)d_out;

  unsigned short* qb   = (unsigned short*)d_ws;                                  // 16,777,216 el
  unsigned short* wb   = (unsigned short*)((char*)d_ws + 33554432);              //  3,145,728 el
  unsigned short* qkvb = (unsigned short*)((char*)d_ws + 39845888);              // 50,331,648 el

  cast_kernel<<<16384, 256, 0, stream>>>(query, qb, 16777216);
  cast_kernel<<<3072, 256, 0, stream>>>(Wqkv, wb, 3145728);

  gemm_qkv<<<768, 512, 0, stream>>>(qb, wb, bqkv, qkvb);

  attn_kernel<<<4096, 256, 0, stream>>>(qkvb, mask, out);
}

// Round 5
// 318.108 us; speedup vs baseline: 1.0773x; 1.0773x over previous
//
#include <hip/hip_runtime.h>
#include <cstdint>
#include <cstddef>

// Problem: B=4, S=4096, HID=1024, H=16, DH=64
//   qkv = query @ W^T + b    (M=16384, N=3072, K=1024)
//   per-position (b,s): scores = q(16x64) @ k^T /8 + mask(16x16); softmax; o = p @ v(16x64)
// Pipeline: cast fp32->bf16 (query, W) -> MFMA GEMM (bf16, fp32 acc, +bias, store bf16)
//           -> per-position MFMA attention -> out fp32.
//
// GEMM (reverted to the best-measured R1 schedule: 110 us, MfmaUtil 41%):
// 256x256 tile, BK=64, 8 waves (2M x 4N), 4-phase-per-K-tile pipelined schedule with
// counted vmcnt (never 0 in the main loop); barrier-pair per phase; i-outer epilogue
// (measured clean 98 MB WRITE_SIZE; j-outer measured 187 MB partial-line RMW).
//
// ATTENTION (rewritten, MFMA): per position one wave.
//   S[g][h] = sum_d k[g][d] q[h][d]  via  mfma_16x16x32_bf16(A=K, B=Q^T) x2 (d=0..63).
//   Swapped operands make P's C-fragment (lane: col=h=lane&15, row=g=(lane>>4)*4+r)
//   EXACTLY the A-fragment layout of mfma_16x16x16_bf16 for PV -> zero cross-lane.
//   Q,K A/B-fragments are per-lane 16B contiguous in global -> direct loads, no LDS.
//   Only V staged in LDS (2 KB/wave, linear DMA); PV B-frag = 16 ds_read_u16 (k-major).
//   Softmax: row-reduce = 3 fmax + shfl_xor(16,32); P pre-scaled by 1/sum, bf16-packed.
// ws layout: Qb bf16 [16M el] @0 ; Wb bf16 [3M el] @33554432 ; QKVb bf16 [48M el] @39845888

typedef __attribute__((ext_vector_type(8))) short bf16x8;
typedef __attribute__((ext_vector_type(4))) short bf16x4;
typedef __attribute__((ext_vector_type(4))) float f32x4;

__device__ inline unsigned short f2bf(float f) {
  unsigned int i = __float_as_uint(f);
  i += 0x7fff + ((i >> 16) & 1);   // RNE
  return (unsigned short)(i >> 16);
}

__device__ inline void async16(const void* g, void* l) {
  __builtin_amdgcn_global_load_lds(
      (const __attribute__((address_space(1))) void*)g,
      (__attribute__((address_space(3))) void*)l, 16, 0, 0);
}

// ---------------- cast fp32 -> bf16, 4 elems/thread ----------------
__global__ __launch_bounds__(256) void cast_kernel(const float* __restrict__ in,
                                                   unsigned short* __restrict__ out,
                                                   int n) {
  int i = (blockIdx.x * 256 + threadIdx.x) * 4;
  if (i >= n) return;
  float4 v = *(const float4*)(in + i);
  union { unsigned short u[4]; unsigned long long ll; } o;
  o.u[0] = f2bf(v.x); o.u[1] = f2bf(v.y); o.u[2] = f2bf(v.z); o.u[3] = f2bf(v.w);
  *(unsigned long long*)(out + i) = o.ll;
}

// ---------------- GEMM: C[M=16384][N=3072] = A[M][1024] * B[N][1024]^T + bias ----------------
#define GK 1024
#define GN 3072
__global__ __launch_bounds__(512, 2) void gemm_qkv(const unsigned short* __restrict__ A,
                                                   const unsigned short* __restrict__ Bm,
                                                   const float* __restrict__ bias,
                                                   unsigned short* __restrict__ C) {
  // double-buffered 256x64 tiles of A and B: 2 * 2 * 32 KiB = 128 KiB LDS
  __shared__ unsigned short As[2][256][64];
  __shared__ unsigned short Bs[2][256][64];

  // XCD-bijective swizzle (768 blocks % 8 == 0), n-fast within each XCD chunk.
  const int bid = blockIdx.x;
  const int swz = (bid & 7) * 96 + (bid >> 3);
  const int m0 = (swz / 12) * 256;
  const int n0 = (swz % 12) * 256;

  const int tid  = threadIdx.x;
  const int lane = tid & 63;
  const int wave = tid >> 6;
  const int wm = wave & 1;        // 2 waves in M
  const int wn = wave >> 1;       // 4 waves in N
  const int fr = lane & 15;
  const int fq = lane >> 4;

  // staging geometry: slot = rho*512 + tid; row = slot>>3; chunk = (slot&7)^(row&7).
  const int r0 = tid >> 3;
  const int c0 = (tid & 7) ^ (r0 & 7);
  const unsigned short* gA = A  + (size_t)(m0 + r0) * GK + c0 * 8;
  const unsigned short* gB = Bm + (size_t)(n0 + r0) * GK + c0 * 8;
  const int ls0 = wave * 512;

#define STAGE_A(tt, hh) do {                                                   \
    unsigned short* lb_ = &As[(tt) & 1][(hh) * 128][0];                        \
    const unsigned short* g_ = gA + (size_t)(hh) * 128 * GK + (tt) * 64;       \
    async16(g_, lb_ + ls0);                                                    \
    async16(g_ + (size_t)64 * GK, lb_ + 4096 + ls0);                           \
  } while (0)
#define STAGE_B(tt, hh) do {                                                   \
    unsigned short* lb_ = &Bs[(tt) & 1][(hh) * 128][0];                        \
    const unsigned short* g_ = gB + (size_t)(hh) * 128 * GK + (tt) * 64;       \
    async16(g_, lb_ + ls0);                                                    \
    async16(g_ + (size_t)64 * GK, lb_ + 4096 + ls0);                           \
  } while (0)

  f32x4 acc[8][4] = {};

  // prologue: tile0 fully; tile1 all but A.h1 (that lands at W(0).p0) = 14 loads
  STAGE_A(0, 0); STAGE_A(0, 1); STAGE_B(0, 0); STAGE_B(0, 1);
  STAGE_B(1, 0); STAGE_A(1, 0); STAGE_B(1, 1);

  for (int t = 0; t < 16; ++t) {
    const int cur = t & 1;
    if (t == 0)       { asm volatile("s_waitcnt vmcnt(6)" ::: "memory"); }
    else if (t == 15) { asm volatile("s_waitcnt vmcnt(0)" ::: "memory"); }
    else              { asm volatile("s_waitcnt vmcnt(8)" ::: "memory"); }
    __builtin_amdgcn_s_barrier();
    __builtin_amdgcn_sched_barrier(0);

    bf16x8 bfr[4][2];
    #pragma unroll
    for (int p = 0; p < 4; ++p) {
      bf16x8 af[2][2];
      #pragma unroll
      for (int ii = 0; ii < 2; ++ii) {
        const int rA = (p * 2 + ii) * 32 + wm * 16 + fr;
        #pragma unroll
        for (int ks = 0; ks < 2; ++ks)
          af[ii][ks] = *(const bf16x8*)&As[cur][rA][((ks * 4 + fq) ^ (rA & 7)) * 8];
      }
      if (p == 0) {
        #pragma unroll
        for (int j = 0; j < 4; ++j) {
          const int rB = wn * 64 + j * 16 + fr;
          #pragma unroll
          for (int ks = 0; ks < 2; ++ks)
            bfr[j][ks] = *(const bf16x8*)&Bs[cur][rB][((ks * 4 + fq) ^ (rB & 7)) * 8];
        }
        if (t + 1 < 16) { STAGE_A(t + 1, 1); }
      }
      if (p == 1) {
        asm volatile("s_waitcnt vmcnt(8)" ::: "memory");
      }
      if (p == 2 && t + 2 < 16) { STAGE_B(t + 2, 0); }
      if (p == 3 && t + 2 < 16) { STAGE_A(t + 2, 0); STAGE_B(t + 2, 1); }

      __builtin_amdgcn_s_barrier();
      __builtin_amdgcn_sched_barrier(0);
      __builtin_amdgcn_s_setprio(1);
      #pragma unroll
      for (int ks = 0; ks < 2; ++ks)
        #pragma unroll
        for (int ii = 0; ii < 2; ++ii)
          #pragma unroll
          for (int j = 0; j < 4; ++j)
            acc[p * 2 + ii][j] = __builtin_amdgcn_mfma_f32_16x16x32_bf16(
                af[ii][ks], bfr[j][ks], acc[p * 2 + ii][j], 0, 0, 0);
      __builtin_amdgcn_s_setprio(0);
      __builtin_amdgcn_sched_barrier(0);
    }
  }
#undef STAGE_A
#undef STAGE_B

  // epilogue: bias + bf16 store; i-outer (measured 98 MB WRITE_SIZE; j-outer was 187 MB)
  #pragma unroll
  for (int i = 0; i < 8; ++i) {
    #pragma unroll
    for (int j = 0; j < 4; ++j) {
      const int col = n0 + wn * 64 + j * 16 + fr;
      const float bc = bias[col];
      const int rowb = m0 + i * 32 + wm * 16 + fq * 4;
      #pragma unroll
      for (int rr = 0; rr < 4; ++rr)
        C[(size_t)(rowb + rr) * GN + col] = f2bf(acc[i][j][rr] + bc);
    }
  }
}

// ---------------- per-position MFMA attention ----------------
// one wave per position.  hn = lane&15, grp = lane>>4.
//   QK: S = mfma_16x16x32_bf16(A=K, B=Q^T) x2  ->  S[g=grp*4+r][h=hn] in C-frag
//   softmax over g: 3 fmax + shfl_xor(16,32); p = exp(s-m)/sum, bf16-packed
//   PV: o[h][d] = sum_g P[g][h] v[g][d]: A-frag(P) = C-frag(S) verbatim (zero shuffles);
//       B-frag(V) = v[grp*4+j][db*16+hn] via 4 ds_read_u16 per 16-wide d-block.
__global__ __launch_bounds__(256, 8) void attn_kernel(const unsigned short* __restrict__ QKV,
                                                      const float* __restrict__ mask,
                                                      float* __restrict__ out) {
  __shared__ unsigned short shV[4][1024];   // per wave: V [16 g][64 d] bf16, linear
  const int wave = threadIdx.x >> 6;
  const int lane = threadIdx.x & 63;
  const int pos = blockIdx.x * 4 + wave;

  const unsigned short* row = QKV + (size_t)pos * 3072;

  // ---- stage V (1024 bf16 = 2 KB) via 2 DMA chunks (wave-private, no barrier)
  async16(&row[2048 + (size_t)lane * 8], &shV[wave][0]);
  async16(&row[2048 + 512 + (size_t)lane * 8], &shV[wave][512]);

  const int hn  = lane & 15;    // h for QK (B n-index / C col), d-low for PV
  const int grp = lane >> 4;    // k-group

  // ---- Q B-frag / K A-frag: per-lane 16B contiguous, straight from global
  const int qk_off = hn * 64 + grp * 8;
  bf16x8 qf0 = *(const bf16x8*)&row[qk_off];             // q[h=hn][d: grp*8..+8)
  bf16x8 qf1 = *(const bf16x8*)&row[qk_off + 32];        // d: 32+grp*8..
  bf16x8 kf0 = *(const bf16x8*)&row[1024 + qk_off];      // k[g=hn][d: grp*8..+8)
  bf16x8 kf1 = *(const bf16x8*)&row[1024 + qk_off + 32];

  // ---- mask[pos][h=hn][g=grp*4 + i]: one coalesced float4 per lane
  float4 mk = *(const float4*)&mask[(size_t)pos * 256 + hn * 16 + grp * 4];

  // ---- S[g][h] = sum_d k[g][d] q[h][d]
  f32x4 s = {};
  s = __builtin_amdgcn_mfma_f32_16x16x32_bf16(kf0, qf0, s, 0, 0, 0);
  s = __builtin_amdgcn_mfma_f32_16x16x32_bf16(kf1, qf1, s, 0, 0, 0);

  // ---- softmax over g (rows): lane holds s[g=grp*4+r][h=hn], r=0..3
  float sv0 = s[0] * 0.125f + mk.x;
  float sv1 = s[1] * 0.125f + mk.y;
  float sv2 = s[2] * 0.125f + mk.z;
  float sv3 = s[3] * 0.125f + mk.w;
  float mx = fmaxf(fmaxf(sv0, sv1), fmaxf(sv2, sv3));
  mx = fmaxf(mx, __shfl_xor(mx, 16));
  mx = fmaxf(mx, __shfl_xor(mx, 32));
  float p0 = __expf(sv0 - mx), p1 = __expf(sv1 - mx);
  float p2 = __expf(sv2 - mx), p3 = __expf(sv3 - mx);
  float sum = p0 + p1 + p2 + p3;
  sum += __shfl_xor(sum, 16);
  sum += __shfl_xor(sum, 32);
  const float inv = 1.f / sum;

  // ---- pack P*(1/sum) -> bf16 A-frag for PV (k=g=grp*4+j, m=h=hn): zero cross-lane
  union { unsigned u[2]; bf16x4 v; } pa;
  pa.u[0] = (unsigned)f2bf(p0 * inv) | ((unsigned)f2bf(p1 * inv) << 16);
  pa.u[1] = (unsigned)f2bf(p2 * inv) | ((unsigned)f2bf(p3 * inv) << 16);

  asm volatile("s_waitcnt vmcnt(0)" ::: "memory");   // V DMA complete (oldest in queue)

  float* obase = out + (size_t)pos * 1024 + grp * 256 + hn;
  const unsigned short* vb = &shV[wave][grp * 256];  // rows g = grp*4 .. +4
  #pragma unroll
  for (int db = 0; db < 4; ++db) {
    const int e0 = db * 16 + hn;                     // v[grp*4+j][db*16+hn], j stride 64
#if __has_builtin(__builtin_amdgcn_mfma_f32_16x16x16bf16_1k)
    unsigned v0 = vb[e0], v1 = vb[e0 + 64], v2 = vb[e0 + 128], v3 = vb[e0 + 192];
    union { unsigned u[2]; bf16x4 v; } bfv;
    bfv.u[0] = v0 | (v1 << 16);
    bfv.u[1] = v2 | (v3 << 16);
    f32x4 z = {};
    f32x4 o4 = __builtin_amdgcn_mfma_f32_16x16x16bf16_1k(pa.v, bfv.v, z, 0, 0, 0);
#else
    // fallback: 16x16x32 with zero-padded k>=16.  A: k=grp*8+j -> quads 2*grp, 2*grp+1
    // held by lanes grp*32+hn and grp*32+16+hn; zero for grp>=2.
    const int src = grp * 32 + hn;
    unsigned a0 = __shfl((int)pa.u[0], src), a1 = __shfl((int)pa.u[1], src);
    unsigned a2 = __shfl((int)pa.u[0], src + 16), a3 = __shfl((int)pa.u[1], src + 16);
    if (grp >= 2) { a0 = a1 = a2 = a3 = 0; }
    union { unsigned u[4]; bf16x8 v; } paw;
    paw.u[0] = a0; paw.u[1] = a1; paw.u[2] = a2; paw.u[3] = a3;
    // B: k=(grp*8+j)&15 (finite re-reads for the zeroed half)
    const unsigned short* vbf = &shV[wave][((grp & 1) * 8) * 64];
    unsigned w0 = vbf[e0],       w1 = vbf[e0 + 64],  w2 = vbf[e0 + 128], w3 = vbf[e0 + 192];
    unsigned w4 = vbf[e0 + 256], w5 = vbf[e0 + 320], w6 = vbf[e0 + 384], w7 = vbf[e0 + 448];
    union { unsigned u[4]; bf16x8 v; } bfv;
    bfv.u[0] = w0 | (w1 << 16); bfv.u[1] = w2 | (w3 << 16);
    bfv.u[2] = w4 | (w5 << 16); bfv.u[3] = w6 | (w7 << 16);
    f32x4 z = {};
    f32x4 o4 = __builtin_amdgcn_mfma_f32_16x16x32_bf16(paw.v, bfv.v, z, 0, 0, 0);
#endif
    // store: o[h=grp*4+r][d=db*16+hn] fp32
    #pragma unroll
    for (int r = 0; r < 4; ++r)
      obase[r * 64 + db * 16] = o4[r];
  }
}

extern "C" void kernel_launch(void* const* d_in, const int* in_sizes, int n_in,
                              void* d_out, int out_size, void* d_ws, size_t ws_size,
                              hipStream_t stream) {
  const float* query = (const float*)d_in[0];
  // d_in[1] (key) and d_in[2] (value) are unused by the reference.
  const float* mask  = (const float*)d_in[3];
  const float* Wqkv  = (const float*)d_in[4];
  const float* bqkv  = (const float*)d_in[5];
  float* out = (float*)d_out;

  unsigned short* qb   = (unsigned short*)d_ws;                                  // 16,777,216 el
  unsigned short* wb   = (unsigned short*)((char*)d_ws + 33554432);              //  3,145,728 el
  unsigned short* qkvb = (unsigned short*)((char*)d_ws + 39845888);              // 50,331,648 el

  cast_kernel<<<16384, 256, 0, stream>>>(query, qb, 16777216);
  cast_kernel<<<3072, 256, 0, stream>>>(Wqkv, wb, 3145728);

  gemm_qkv<<<768, 512, 0, stream>>>(qb, wb, bqkv, qkvb);

  attn_kernel<<<4096, 256, 0, stream>>>(qkvb, mask, out);
}

// Round 6
// 315.936 us; speedup vs baseline: 1.0847x; 1.0069x over previous
//
#include <hip/hip_runtime.h>
#include <cstdint>
#include <cstddef>

// Problem: B=4, S=4096, HID=1024, H=16, DH=64
//   qkv = query @ W^T + b    (M=16384, N=3072, K=1024)
//   per-position (b,s): scores = q(16x64) @ k^T /8 + mask(16x16); softmax; o = p @ v(16x64)
// Pipeline: fused cast fp32->bf16 (query+W, one launch) -> MFMA GEMM (bf16, fp32 acc,
//           +bias, store bf16) -> per-position MFMA attention -> out fp32.
//
// GEMM (R1 schedule, best of 4 measured variants: 106 us, MfmaUtil 40%, 972 TF):
// 256x256 tile, BK=64, 8 waves (2M x 4N), 4-phase-per-K-tile pipelined schedule with
// counted vmcnt (never 0 in the main loop); barrier-pair per phase; i-outer epilogue
// (measured clean 98 MB WRITE_SIZE; j-outer measured 187 MB partial-line RMW).
//
// ATTENTION (MFMA, per position one wave):
//   QK: S = mfma_16x16x32_bf16(A=K, B=Q^T) x2  ->  S[g=grp*4+r][h=hn] in C-frag.
//   softmax over g: 3 fmax + shfl_xor(16,32); p = exp(s-m)/sum, bf16-packed (pa).
//   PV (operand-SWAPPED vs R4): O^T = mfma_16x16x16_bf16(A=V-frag, B=pa) so each lane
//   holds o[h=hn][d = db*16 + grp*4 + r], r=0..3 consecutive -> 4x float4 stores/lane
//   (R4's order gave 16 scalar dword stores).  A/B frags of 16x16x16 are lane-symmetric,
//   so the SAME 4 ds_read_u16 (V) and the SAME pa pack feed the swapped call.
//   NOTE: no __launch_bounds__ min-waves — R4's (256,8) capped VGPR at 64 and risked
//   scratch spills in a latency-bound kernel; natural allocation gives 8 waves/SIMD.
// ws layout: Qb bf16 [16M el] @0 ; Wb bf16 [3M el] @33554432 ; QKVb bf16 [48M el] @39845888

typedef __attribute__((ext_vector_type(8))) short bf16x8;
typedef __attribute__((ext_vector_type(4))) short bf16x4;
typedef __attribute__((ext_vector_type(4))) float f32x4;

__device__ inline unsigned short f2bf(float f) {
  unsigned int i = __float_as_uint(f);
  i += 0x7fff + ((i >> 16) & 1);   // RNE
  return (unsigned short)(i >> 16);
}

__device__ inline void async16(const void* g, void* l) {
  __builtin_amdgcn_global_load_lds(
      (const __attribute__((address_space(1))) void*)g,
      (__attribute__((address_space(3))) void*)l, 16, 0, 0);
}

// ---------------- fused cast fp32 -> bf16 (query then W), 4 elems/thread ----------------
// n0 = 16777216 is a multiple of 1024 (block quantum), so no block straddles the seam.
__global__ __launch_bounds__(256) void cast2_kernel(const float* __restrict__ in0,
                                                    unsigned short* __restrict__ out0,
                                                    int n0,
                                                    const float* __restrict__ in1,
                                                    unsigned short* __restrict__ out1,
                                                    int n1) {
  int i = (blockIdx.x * 256 + threadIdx.x) * 4;
  const float* src; unsigned short* dst;
  if (i < n0) { src = in0 + i; dst = out0 + i; }
  else {
    int j = i - n0;
    if (j >= n1) return;
    src = in1 + j; dst = out1 + j;
  }
  float4 v = *(const float4*)src;
  union { unsigned short u[4]; unsigned long long ll; } o;
  o.u[0] = f2bf(v.x); o.u[1] = f2bf(v.y); o.u[2] = f2bf(v.z); o.u[3] = f2bf(v.w);
  *(unsigned long long*)dst = o.ll;
}

// ---------------- GEMM: C[M=16384][N=3072] = A[M][1024] * B[N][1024]^T + bias ----------------
#define GK 1024
#define GN 3072
__global__ __launch_bounds__(512, 2) void gemm_qkv(const unsigned short* __restrict__ A,
                                                   const unsigned short* __restrict__ Bm,
                                                   const float* __restrict__ bias,
                                                   unsigned short* __restrict__ C) {
  // double-buffered 256x64 tiles of A and B: 2 * 2 * 32 KiB = 128 KiB LDS
  __shared__ unsigned short As[2][256][64];
  __shared__ unsigned short Bs[2][256][64];

  // XCD-bijective swizzle (768 blocks % 8 == 0), n-fast within each XCD chunk.
  const int bid = blockIdx.x;
  const int swz = (bid & 7) * 96 + (bid >> 3);
  const int m0 = (swz / 12) * 256;
  const int n0 = (swz % 12) * 256;

  const int tid  = threadIdx.x;
  const int lane = tid & 63;
  const int wave = tid >> 6;
  const int wm = wave & 1;        // 2 waves in M
  const int wn = wave >> 1;       // 4 waves in N
  const int fr = lane & 15;
  const int fq = lane >> 4;

  // staging geometry: slot = rho*512 + tid; row = slot>>3; chunk = (slot&7)^(row&7).
  const int r0 = tid >> 3;
  const int c0 = (tid & 7) ^ (r0 & 7);
  const unsigned short* gA = A  + (size_t)(m0 + r0) * GK + c0 * 8;
  const unsigned short* gB = Bm + (size_t)(n0 + r0) * GK + c0 * 8;
  const int ls0 = wave * 512;

#define STAGE_A(tt, hh) do {                                                   \
    unsigned short* lb_ = &As[(tt) & 1][(hh) * 128][0];                        \
    const unsigned short* g_ = gA + (size_t)(hh) * 128 * GK + (tt) * 64;       \
    async16(g_, lb_ + ls0);                                                    \
    async16(g_ + (size_t)64 * GK, lb_ + 4096 + ls0);                           \
  } while (0)
#define STAGE_B(tt, hh) do {                                                   \
    unsigned short* lb_ = &Bs[(tt) & 1][(hh) * 128][0];                        \
    const unsigned short* g_ = gB + (size_t)(hh) * 128 * GK + (tt) * 64;       \
    async16(g_, lb_ + ls0);                                                    \
    async16(g_ + (size_t)64 * GK, lb_ + 4096 + ls0);                           \
  } while (0)

  f32x4 acc[8][4] = {};

  // prologue: tile0 fully; tile1 all but A.h1 (that lands at W(0).p0) = 14 loads
  STAGE_A(0, 0); STAGE_A(0, 1); STAGE_B(0, 0); STAGE_B(0, 1);
  STAGE_B(1, 0); STAGE_A(1, 0); STAGE_B(1, 1);

  for (int t = 0; t < 16; ++t) {
    const int cur = t & 1;
    if (t == 0)       { asm volatile("s_waitcnt vmcnt(6)" ::: "memory"); }
    else if (t == 15) { asm volatile("s_waitcnt vmcnt(0)" ::: "memory"); }
    else              { asm volatile("s_waitcnt vmcnt(8)" ::: "memory"); }
    __builtin_amdgcn_s_barrier();
    __builtin_amdgcn_sched_barrier(0);

    bf16x8 bfr[4][2];
    #pragma unroll
    for (int p = 0; p < 4; ++p) {
      bf16x8 af[2][2];
      #pragma unroll
      for (int ii = 0; ii < 2; ++ii) {
        const int rA = (p * 2 + ii) * 32 + wm * 16 + fr;
        #pragma unroll
        for (int ks = 0; ks < 2; ++ks)
          af[ii][ks] = *(const bf16x8*)&As[cur][rA][((ks * 4 + fq) ^ (rA & 7)) * 8];
      }
      if (p == 0) {
        #pragma unroll
        for (int j = 0; j < 4; ++j) {
          const int rB = wn * 64 + j * 16 + fr;
          #pragma unroll
          for (int ks = 0; ks < 2; ++ks)
            bfr[j][ks] = *(const bf16x8*)&Bs[cur][rB][((ks * 4 + fq) ^ (rB & 7)) * 8];
        }
        if (t + 1 < 16) { STAGE_A(t + 1, 1); }
      }
      if (p == 1) {
        asm volatile("s_waitcnt vmcnt(8)" ::: "memory");
      }
      if (p == 2 && t + 2 < 16) { STAGE_B(t + 2, 0); }
      if (p == 3 && t + 2 < 16) { STAGE_A(t + 2, 0); STAGE_B(t + 2, 1); }

      __builtin_amdgcn_s_barrier();
      __builtin_amdgcn_sched_barrier(0);
      __builtin_amdgcn_s_setprio(1);
      #pragma unroll
      for (int ks = 0; ks < 2; ++ks)
        #pragma unroll
        for (int ii = 0; ii < 2; ++ii)
          #pragma unroll
          for (int j = 0; j < 4; ++j)
            acc[p * 2 + ii][j] = __builtin_amdgcn_mfma_f32_16x16x32_bf16(
                af[ii][ks], bfr[j][ks], acc[p * 2 + ii][j], 0, 0, 0);
      __builtin_amdgcn_s_setprio(0);
      __builtin_amdgcn_sched_barrier(0);
    }
  }
#undef STAGE_A
#undef STAGE_B

  // epilogue: bias + bf16 store; i-outer (measured 98 MB WRITE_SIZE; j-outer was 187 MB)
  #pragma unroll
  for (int i = 0; i < 8; ++i) {
    #pragma unroll
    for (int j = 0; j < 4; ++j) {
      const int col = n0 + wn * 64 + j * 16 + fr;
      const float bc = bias[col];
      const int rowb = m0 + i * 32 + wm * 16 + fq * 4;
      #pragma unroll
      for (int rr = 0; rr < 4; ++rr)
        C[(size_t)(rowb + rr) * GN + col] = f2bf(acc[i][j][rr] + bc);
    }
  }
}

// ---------------- per-position MFMA attention ----------------
// one wave per position.  hn = lane&15, grp = lane>>4.
__global__ __launch_bounds__(256) void attn_kernel(const unsigned short* __restrict__ QKV,
                                                   const float* __restrict__ mask,
                                                   float* __restrict__ out) {
  __shared__ unsigned short shV[4][1024];   // per wave: V [16 g][64 d] bf16, linear
  const int wave = threadIdx.x >> 6;
  const int lane = threadIdx.x & 63;
  const int pos = blockIdx.x * 4 + wave;

  const unsigned short* row = QKV + (size_t)pos * 3072;

  // ---- stage V (1024 bf16 = 2 KB) via 2 DMA chunks (wave-private, no barrier)
  async16(&row[2048 + (size_t)lane * 8], &shV[wave][0]);
  async16(&row[2048 + 512 + (size_t)lane * 8], &shV[wave][512]);

  const int hn  = lane & 15;    // h for QK (B n-index / C col), d-low for PV A-frag
  const int grp = lane >> 4;    // k-group

  // ---- Q B-frag / K A-frag: per-lane 16B contiguous, straight from global
  const int qk_off = hn * 64 + grp * 8;
  bf16x8 qf0 = *(const bf16x8*)&row[qk_off];             // q[h=hn][d: grp*8..+8)
  bf16x8 qf1 = *(const bf16x8*)&row[qk_off + 32];        // d: 32+grp*8..
  bf16x8 kf0 = *(const bf16x8*)&row[1024 + qk_off];      // k[g=hn][d: grp*8..+8)
  bf16x8 kf1 = *(const bf16x8*)&row[1024 + qk_off + 32];

  // ---- mask[pos][h=hn][g=grp*4 + i]: one coalesced float4 per lane
  float4 mk = *(const float4*)&mask[(size_t)pos * 256 + hn * 16 + grp * 4];

  // ---- S[g][h] = sum_d k[g][d] q[h][d]
  f32x4 s = {};
  s = __builtin_amdgcn_mfma_f32_16x16x32_bf16(kf0, qf0, s, 0, 0, 0);
  s = __builtin_amdgcn_mfma_f32_16x16x32_bf16(kf1, qf1, s, 0, 0, 0);

  // ---- softmax over g (rows): lane holds s[g=grp*4+r][h=hn], r=0..3
  float sv0 = s[0] * 0.125f + mk.x;
  float sv1 = s[1] * 0.125f + mk.y;
  float sv2 = s[2] * 0.125f + mk.z;
  float sv3 = s[3] * 0.125f + mk.w;
  float mx = fmaxf(fmaxf(sv0, sv1), fmaxf(sv2, sv3));
  mx = fmaxf(mx, __shfl_xor(mx, 16));
  mx = fmaxf(mx, __shfl_xor(mx, 32));
  float p0 = __expf(sv0 - mx), p1 = __expf(sv1 - mx);
  float p2 = __expf(sv2 - mx), p3 = __expf(sv3 - mx);
  float sum = p0 + p1 + p2 + p3;
  sum += __shfl_xor(sum, 16);
  sum += __shfl_xor(sum, 32);
  const float inv = 1.f / sum;

  // ---- pack P*(1/sum) -> bf16 frag (element j at lane (hn,grp) = P[g=grp*4+j][h=hn])
  union { unsigned u[2]; bf16x4 v; } pa;
  pa.u[0] = (unsigned)f2bf(p0 * inv) | ((unsigned)f2bf(p1 * inv) << 16);
  pa.u[1] = (unsigned)f2bf(p2 * inv) | ((unsigned)f2bf(p3 * inv) << 16);

  asm volatile("s_waitcnt vmcnt(0)" ::: "memory");   // V DMA complete (oldest in queue)

  const unsigned short* vb = &shV[wave][grp * 256];  // rows g = grp*4 .. +4
  #pragma unroll
  for (int db = 0; db < 4; ++db) {
    const int e0 = db * 16 + hn;                     // v[grp*4+j][db*16+hn], j stride 64
    unsigned v0 = vb[e0], v1 = vb[e0 + 64], v2 = vb[e0 + 128], v3 = vb[e0 + 192];
    union { unsigned u[2]; bf16x4 v; } bfv;
    bfv.u[0] = v0 | (v1 << 16);
    bfv.u[1] = v2 | (v3 << 16);
    f32x4 z = {};
#if __has_builtin(__builtin_amdgcn_mfma_f32_16x16x16bf16_1k)
    // O^T = V^T @ P: A-frag = bfv (A[m=hn][k=g] = v[g][db*16+hn]),
    //               B-frag = pa  (B[k=g][n=hn] = P[g][hn]).
    // C: lane holds o[h=hn][d = db*16 + grp*4 + r], r=0..3 -> ONE float4 store.
    f32x4 o4 = __builtin_amdgcn_mfma_f32_16x16x16bf16_1k(bfv.v, pa.v, z, 0, 0, 0);
    *(float4*)(out + (size_t)pos * 1024 + hn * 64 + db * 16 + grp * 4) =
        *(const float4*)&o4;
#else
    // fallback (R4-verified path): o[h][d] via 16x16x32 with zero-padded k>=16,
    // scalar stores.  A: k=grp*8+j -> quads 2*grp, 2*grp+1 held by lanes grp*32+hn
    // and grp*32+16+hn; zero for grp>=2.
    const int src = grp * 32 + hn;
    unsigned a0 = __shfl((int)pa.u[0], src), a1 = __shfl((int)pa.u[1], src);
    unsigned a2 = __shfl((int)pa.u[0], src + 16), a3 = __shfl((int)pa.u[1], src + 16);
    if (grp >= 2) { a0 = a1 = a2 = a3 = 0; }
    union { unsigned u[4]; bf16x8 v; } paw;
    paw.u[0] = a0; paw.u[1] = a1; paw.u[2] = a2; paw.u[3] = a3;
    const unsigned short* vbf = &shV[wave][((grp & 1) * 8) * 64];
    unsigned w0 = vbf[e0],       w1 = vbf[e0 + 64],  w2 = vbf[e0 + 128], w3 = vbf[e0 + 192];
    unsigned w4 = vbf[e0 + 256], w5 = vbf[e0 + 320], w6 = vbf[e0 + 384], w7 = vbf[e0 + 448];
    union { unsigned u[4]; bf16x8 v; } bfw;
    bfw.u[0] = w0 | (w1 << 16); bfw.u[1] = w2 | (w3 << 16);
    bfw.u[2] = w4 | (w5 << 16); bfw.u[3] = w6 | (w7 << 16);
    f32x4 o4 = __builtin_amdgcn_mfma_f32_16x16x32_bf16(paw.v, bfw.v, z, 0, 0, 0);
    #pragma unroll
    for (int r = 0; r < 4; ++r)
      out[(size_t)pos * 1024 + (grp * 4 + r) * 64 + db * 16 + hn] = o4[r];
#endif
  }
}

extern "C" void kernel_launch(void* const* d_in, const int* in_sizes, int n_in,
                              void* d_out, int out_size, void* d_ws, size_t ws_size,
                              hipStream_t stream) {
  const float* query = (const float*)d_in[0];
  // d_in[1] (key) and d_in[2] (value) are unused by the reference.
  const float* mask  = (const float*)d_in[3];
  const float* Wqkv  = (const float*)d_in[4];
  const float* bqkv  = (const float*)d_in[5];
  float* out = (float*)d_out;

  unsigned short* qb   = (unsigned short*)d_ws;                                  // 16,777,216 el
  unsigned short* wb   = (unsigned short*)((char*)d_ws + 33554432);              //  3,145,728 el
  unsigned short* qkvb = (unsigned short*)((char*)d_ws + 39845888);              // 50,331,648 el

  cast2_kernel<<<19456, 256, 0, stream>>>(query, qb, 16777216, Wqkv, wb, 3145728);

  gemm_qkv<<<768, 512, 0, stream>>>(qb, wb, bqkv, qkvb);

  attn_kernel<<<4096, 256, 0, stream>>>(qkvb, mask, out);
}